// Round 1
// baseline (330.802 us; speedup 1.0000x reference)
//
#include <hip/hip_runtime.h>

#define MM 24
#define ROW_LEN (MM + 1)                       // 25 floats per row
#define RPB 256                                // rows per block = threads per block
#define FPB (RPB * ROW_LEN)                    // 6400 floats of LDS per block
#define V4PB (FPB / 4)                         // 1600 float4 per block

__global__ __launch_bounds__(RPB)
void lpc_stab_kernel(const float* __restrict__ a, float* __restrict__ out, int B) {
    __shared__ float lds[FPB];

    const long long total4 = ((long long)B * ROW_LEN) >> 2;   // B*25 divisible by 4
    const long long base4  = (long long)blockIdx.x * V4PB;
    const float4* a4 = (const float4*)a;
    float4*       o4 = (float4*)out;
    float4*       l4 = (float4*)lds;

    // ---- coalesced global -> LDS (float4) ----
    #pragma unroll
    for (int it = 0; it < 7; ++it) {
        int li = it * RPB + threadIdx.x;
        if (li < V4PB) {
            long long g = base4 + li;
            if (g < total4) l4[li] = a4[g];
        }
    }
    __syncthreads();

    const int row = blockIdx.x * RPB + threadIdx.x;
    if (row < B) {
        float* p = lds + threadIdx.x * ROW_LEN;   // stride 25: conflict-free (gcd(25,32)=1)
        float K = p[0];
        float c[MM], k[MM];
        #pragma unroll
        for (int j = 0; j < MM; ++j) c[j] = p[j + 1];

        // ---- step-down (LPC -> reflection coefficients) ----
        #pragma unroll
        for (int m = MM; m >= 1; --m) {
            float km = c[m - 1];
            k[m - 1] = km;
            if (m >= 2) {
                float inv = __builtin_amdgcn_rcpf(1.0f - km * km);
                #pragma unroll
                for (int i = 0; i < (m - 1) / 2; ++i) {
                    float x = c[i], y = c[m - 2 - i];
                    c[i]         = (x - km * y) * inv;
                    c[m - 2 - i] = (y - km * x) * inv;
                }
                if ((m - 1) & 1) {                 // middle element pairs with itself
                    int i = (m - 1) / 2;
                    float x = c[i];
                    c[i] = (x - km * x) * inv;
                }
            }
        }

        // ---- clip (BOUND == 1.0f in fp32) ----
        #pragma unroll
        for (int j = 0; j < MM; ++j) k[j] = fminf(fmaxf(k[j], -1.0f), 1.0f);

        // ---- step-up (reflection -> LPC), rebuild into c ----
        #pragma unroll
        for (int m = 1; m <= MM; ++m) {
            float km = k[m - 1];
            #pragma unroll
            for (int i = 0; i < (m - 1) / 2; ++i) {
                float x = c[i], y = c[m - 2 - i];
                c[i]         = x + km * y;
                c[m - 2 - i] = y + km * x;
            }
            if ((m >= 2) && ((m - 1) & 1)) {
                int i = (m - 1) / 2;
                c[i] = c[i] + km * c[i];
            }
            c[m - 1] = km;
        }

        // write result back into this thread's own LDS row (no cross-thread hazard)
        p[0] = K;
        #pragma unroll
        for (int j = 0; j < MM; ++j) p[j + 1] = c[j];
    }
    __syncthreads();

    // ---- coalesced LDS -> global (float4) ----
    #pragma unroll
    for (int it = 0; it < 7; ++it) {
        int li = it * RPB + threadIdx.x;
        if (li < V4PB) {
            long long g = base4 + li;
            if (g < total4) o4[g] = l4[li];
        }
    }
}

extern "C" void kernel_launch(void* const* d_in, const int* in_sizes, int n_in,
                              void* d_out, int out_size, void* d_ws, size_t ws_size,
                              hipStream_t stream) {
    const float* a = (const float*)d_in[0];
    float* out = (float*)d_out;
    int B = in_sizes[0] / ROW_LEN;
    int blocks = (B + RPB - 1) / RPB;
    lpc_stab_kernel<<<blocks, RPB, 0, stream>>>(a, out, B);
}